// Round 9
// baseline (259.173 us; speedup 1.0000x reference)
//
#include <hip/hip_runtime.h>

typedef __bf16 bf16;
typedef __attribute__((ext_vector_type(4))) __bf16 bf16x4;
typedef __attribute__((ext_vector_type(8))) __bf16 bf16x8;
typedef __attribute__((ext_vector_type(4))) float f32x4;

#define MFMA(A,B,C) __builtin_amdgcn_mfma_f32_16x16x32_bf16(A,B,C,0,0,0)

#define SEQ 2048
#define EMB 512
#define HD  64
#define SCALE 22.627416997969522f  // sqrt(512): scores are divided by E^-0.5
// Online-softmax seed: not -inf (fast-math folds inf constants to poison).
#define NEG_SEED -3.0e4f
#define LCAP 32                    // per-query candidate ring (power of 2)

// ---------------------------------------------------------------------------
// One-shot fp32 -> bf16 hi/lo conversion (x, W_qkv) and bf16 (W_out).
// Also zeroes Vs (gemm_qkv atomics) and PcntG (attn_scan atomics).
// ---------------------------------------------------------------------------
__global__ __launch_bounds__(256)
void convert_kernel(const float* __restrict__ x, const float* __restrict__ Wqkv,
                    const float* __restrict__ Wout,
                    bf16* __restrict__ Xh, bf16* __restrict__ Xl,
                    bf16* __restrict__ Wqh, bf16* __restrict__ Wql,
                    bf16* __restrict__ Wo, float* __restrict__ Vs,
                    int* __restrict__ PcntG) {
  if (blockIdx.x < 8) Vs[blockIdx.x * 256 + threadIdx.x] = 0.f;        // 32*64
  else if (blockIdx.x < 264)                                           // 65536
    PcntG[(blockIdx.x - 8) * 256 + threadIdx.x] = 0;
  const int NX = 8192 * 512 / 4;   // f32x4 chunks
  const int NW = 1536 * 512 / 4;
  const int NO = 512 * 512 / 4;
  const int stride = gridDim.x * 256;
  for (int i = blockIdx.x * 256 + threadIdx.x; i < NX + NW + NO; i += stride) {
    const float* src; bf16 *dh, *dl; int j; bool haslo;
    if (i < NX)           { src = x;    dh = Xh;  dl = Xl;  j = i;           haslo = true; }
    else if (i < NX + NW) { src = Wqkv; dh = Wqh; dl = Wql; j = i - NX;      haslo = true; }
    else                  { src = Wout; dh = Wo;  dl = Wo;  j = i - NX - NW; haslo = false; }
    f32x4 v = *(const f32x4*)&src[(size_t)j * 4];
    bf16x4 h4, l4;
#pragma unroll
    for (int r = 0; r < 4; ++r) {
      bf16 h = (bf16)v[r]; h4[r] = h; l4[r] = (bf16)(v[r] - (float)h);
    }
    *(bf16x4*)&dh[(size_t)j * 4] = h4;
    if (haslo) *(bf16x4*)&dl[(size_t)j * 4] = l4;
  }
}

// ---------------------------------------------------------------------------
// QKV projection (round-7 proven form): bf16 hi/lo GEMM, 64x64 tiles,
// XCD-stripe swizzle + XOR-chunk LDS. V-tiles hi-only + fused Vs atomics.
// ---------------------------------------------------------------------------
__global__ __launch_bounds__(256)
void gemm_qkv(const bf16* __restrict__ Xh, const bf16* __restrict__ Xl,
              const bf16* __restrict__ Wh, const bf16* __restrict__ Wl,
              const float* __restrict__ bias,
              bf16* __restrict__ Qh, bf16* __restrict__ Ql,
              bf16* __restrict__ Kh, bf16* __restrict__ Kl,
              bf16* __restrict__ Vrm, float* __restrict__ Vs) {
  __shared__ __align__(16) bf16 Ah[64][64], Al[64][64];
  __shared__ __align__(16) bf16 Bh[64][64], Bl[64][64];
  const int tid  = threadIdx.x;
  const int lane = tid & 63, wave = tid >> 6;
  const int lin = blockIdx.x + gridDim.x * blockIdx.y;
  const int xcd = lin & 7;
  const int w_  = lin >> 3;                  // 0..383
  const int m0 = ((w_ & 15) + xcd * 16) * 64;
  const int n0 = (w_ >> 4) * 64;
  const bool isV = ((n0 % 192) == 128);      // V third: hi-only suffices
  const int wm = (wave >> 1) * 32, wn = (wave & 1) * 32;
  const int c = lane & 15, quad = lane >> 4;
  const int sr   = tid >> 3;                 // 0..31 staging row
  const int scol = (tid & 7) * 8;
  const int sphy = ((tid & 7) ^ (sr & 7)) * 8;   // (sr+32)&7 == sr&7

  const f32x4 zero = {0.f, 0.f, 0.f, 0.f};
  f32x4 acc[2][2];
  acc[0][0] = zero; acc[0][1] = zero; acc[1][0] = zero; acc[1][1] = zero;

  for (int k0 = 0; k0 < 512; k0 += 64) {
    *(bf16x8*)&Ah[sr][sphy]      = *(const bf16x8*)&Xh[(size_t)(m0 + sr     ) * 512 + k0 + scol];
    *(bf16x8*)&Ah[sr + 32][sphy] = *(const bf16x8*)&Xh[(size_t)(m0 + sr + 32) * 512 + k0 + scol];
    *(bf16x8*)&Bh[sr][sphy]      = *(const bf16x8*)&Wh[(size_t)(n0 + sr     ) * 512 + k0 + scol];
    *(bf16x8*)&Bh[sr + 32][sphy] = *(const bf16x8*)&Wh[(size_t)(n0 + sr + 32) * 512 + k0 + scol];
    if (!isV) {
      *(bf16x8*)&Al[sr][sphy]      = *(const bf16x8*)&Xl[(size_t)(m0 + sr     ) * 512 + k0 + scol];
      *(bf16x8*)&Al[sr + 32][sphy] = *(const bf16x8*)&Xl[(size_t)(m0 + sr + 32) * 512 + k0 + scol];
      *(bf16x8*)&Bl[sr][sphy]      = *(const bf16x8*)&Wl[(size_t)(n0 + sr     ) * 512 + k0 + scol];
      *(bf16x8*)&Bl[sr + 32][sphy] = *(const bf16x8*)&Wl[(size_t)(n0 + sr + 32) * 512 + k0 + scol];
    }
    __syncthreads();
#pragma unroll
    for (int ks = 0; ks < 64; ks += 32) {
      const int px = (((ks >> 3) + quad) ^ (c & 7)) * 8;
      bf16x8 ah0 = *(bf16x8*)&Ah[wm + c     ][px];
      bf16x8 ah1 = *(bf16x8*)&Ah[wm + 16 + c][px];
      bf16x8 bh0 = *(bf16x8*)&Bh[wn + c     ][px];
      bf16x8 bh1 = *(bf16x8*)&Bh[wn + 16 + c][px];
      if (isV) {
        acc[0][0] = MFMA(ah0, bh0, acc[0][0]);
        acc[0][1] = MFMA(ah0, bh1, acc[0][1]);
        acc[1][0] = MFMA(ah1, bh0, acc[1][0]);
        acc[1][1] = MFMA(ah1, bh1, acc[1][1]);
      } else {
        bf16x8 al0 = *(bf16x8*)&Al[wm + c     ][px];
        bf16x8 al1 = *(bf16x8*)&Al[wm + 16 + c][px];
        bf16x8 bl0 = *(bf16x8*)&Bl[wn + c     ][px];
        bf16x8 bl1 = *(bf16x8*)&Bl[wn + 16 + c][px];
        acc[0][0] = MFMA(ah0, bh0, acc[0][0]);
        acc[0][0] = MFMA(al0, bh0, acc[0][0]);
        acc[0][0] = MFMA(ah0, bl0, acc[0][0]);
        acc[0][1] = MFMA(ah0, bh1, acc[0][1]);
        acc[0][1] = MFMA(al0, bh1, acc[0][1]);
        acc[0][1] = MFMA(ah0, bl1, acc[0][1]);
        acc[1][0] = MFMA(ah1, bh0, acc[1][0]);
        acc[1][0] = MFMA(al1, bh0, acc[1][0]);
        acc[1][0] = MFMA(ah1, bl0, acc[1][0]);
        acc[1][1] = MFMA(ah1, bh1, acc[1][1]);
        acc[1][1] = MFMA(al1, bh1, acc[1][1]);
        acc[1][1] = MFMA(ah1, bl1, acc[1][1]);
      }
    }
    __syncthreads();
  }

  if (isV) {
#pragma unroll
    for (int nt = 0; nt < 2; ++nt) {
      const int n = n0 + wn + nt * 16 + c;
      const float bv = bias[n];
      const int h = n / 192, d = n % 192 - 128;
      const size_t bh = (size_t)((m0 >> 11) * 8 + h);
      float csum = 0.f;
#pragma unroll
      for (int mt = 0; mt < 2; ++mt)
#pragma unroll
        for (int r = 0; r < 4; ++r) {
          const int m = m0 + wm + mt * 16 + quad * 4 + r;
          const int s = m & 2047;
          float v = acc[mt][nt][r] + bv;
          Vrm[(bh * SEQ + s) * HD + d] = (bf16)v;
          csum += v;
        }
      csum += __shfl_xor(csum, 16, 64);
      csum += __shfl_xor(csum, 32, 64);
      if (quad == 0) atomicAdd(&Vs[bh * HD + d], csum);
    }
  } else {
#pragma unroll
    for (int mt = 0; mt < 2; ++mt) {
#pragma unroll
      for (int nt = 0; nt < 2; ++nt) {
        const int n = n0 + wn + nt * 16 + c;
        const float bv = bias[n];
#pragma unroll
        for (int r = 0; r < 4; ++r) {
          const int m = m0 + wm + mt * 16 + quad * 4 + r;
          float v = acc[mt][nt][r] + bv;
          const int h = n / 192, t = n % 192;
          const size_t bh = (size_t)((m >> 11) * 8 + h);
          const int s = m & 2047;
          if (t < 64) {
            float q = v * SCALE;
            bf16 hi = (bf16)q;
            float lo = q - (float)hi;
            size_t idx = (bh * SEQ + s) * HD + t;
            Qh[idx] = hi; Ql[idx] = (bf16)lo;
          } else {
            bf16 hi = (bf16)v;
            float lo = v - (float)hi;
            size_t idx = (bh * SEQ + s) * HD + (t - 64);
            Kh[idx] = hi; Kl[idx] = (bf16)lo;
          }
        }
      }
    }
  }
}

// ---------------------------------------------------------------------------
// Output projection: bf16 x bf16 (pre-converted Wo), fp32 out. Same XOR-swz.
// ---------------------------------------------------------------------------
__global__ __launch_bounds__(256)
void gemm_out(const bf16* __restrict__ A, const bf16* __restrict__ Wo,
              const float* __restrict__ bias, float* __restrict__ C) {
  __shared__ __align__(16) bf16 As[64][64];
  __shared__ __align__(16) bf16 Bs[64][64];
  const int tid  = threadIdx.x;
  const int lane = tid & 63, wave = tid >> 6;
  const int lin = blockIdx.x + gridDim.x * blockIdx.y;
  const int xcd = lin & 7;
  const int w_  = lin >> 3;                  // 0..127
  const int m0 = ((w_ & 15) + xcd * 16) * 64;
  const int n0 = (w_ >> 4) * 64;
  const int wm = (wave >> 1) * 32, wn = (wave & 1) * 32;
  const int c = lane & 15, quad = lane >> 4;
  const int sr   = tid >> 3;
  const int scol = (tid & 7) * 8;
  const int sphy = ((tid & 7) ^ (sr & 7)) * 8;

  const f32x4 zero = {0.f, 0.f, 0.f, 0.f};
  f32x4 acc[2][2];
  acc[0][0] = zero; acc[0][1] = zero; acc[1][0] = zero; acc[1][1] = zero;

  for (int k0 = 0; k0 < 512; k0 += 64) {
    *(bf16x8*)&As[sr][sphy]      = *(const bf16x8*)&A [(size_t)(m0 + sr     ) * 512 + k0 + scol];
    *(bf16x8*)&As[sr + 32][sphy] = *(const bf16x8*)&A [(size_t)(m0 + sr + 32) * 512 + k0 + scol];
    *(bf16x8*)&Bs[sr][sphy]      = *(const bf16x8*)&Wo[(size_t)(n0 + sr     ) * 512 + k0 + scol];
    *(bf16x8*)&Bs[sr + 32][sphy] = *(const bf16x8*)&Wo[(size_t)(n0 + sr + 32) * 512 + k0 + scol];
    __syncthreads();
#pragma unroll
    for (int ks = 0; ks < 64; ks += 32) {
      const int px = (((ks >> 3) + quad) ^ (c & 7)) * 8;
      bf16x8 a0 = *(bf16x8*)&As[wm + c     ][px];
      bf16x8 a1 = *(bf16x8*)&As[wm + 16 + c][px];
      bf16x8 b0 = *(bf16x8*)&Bs[wn + c     ][px];
      bf16x8 b1 = *(bf16x8*)&Bs[wn + 16 + c][px];
      acc[0][0] = MFMA(a0, b0, acc[0][0]);
      acc[0][1] = MFMA(a0, b1, acc[0][1]);
      acc[1][0] = MFMA(a1, b0, acc[1][0]);
      acc[1][1] = MFMA(a1, b1, acc[1][1]);
    }
    __syncthreads();
  }

#pragma unroll
  for (int mt = 0; mt < 2; ++mt) {
#pragma unroll
    for (int nt = 0; nt < 2; ++nt) {
      const int n = n0 + wn + nt * 16 + c;
      const float bv = bias[n];
#pragma unroll
      for (int r = 0; r < 4; ++r) {
        const int m = m0 + wm + mt * 16 + quad * 4 + r;
        C[(size_t)m * 512 + n] = acc[mt][nt][r] + bv;
      }
    }
  }
}

// ---------------------------------------------------------------------------
// Attention SCAN (round-7 structure, key-split x2 for occupancy):
// blockIdx.z owns keys [z*1024, z*1024+1024). Dense staged hi-only scan,
// per-query local running max, window-12 index pushes into GLOBAL per-query
// ring lists (cap 32, counters pre-zeroed). Union-of-windows covers the
// global window: a key with s~ > gmax-12 in half B has s~ > LB-12 (LB<=gmax)
// so B pushes it. Kernel boundary gives cross-XCD visibility for the lists.
// 2048 blocks = 8/CU (16KB LDS) -> 2x the waves of round 7.
// ---------------------------------------------------------------------------
__global__ __launch_bounds__(256, 8)
void attn_scan(const bf16* __restrict__ Qh, const bf16* __restrict__ Kh,
               unsigned short* __restrict__ CandG, int* __restrict__ PcntG) {
  __shared__ __align__(16) bf16 SK[2][64][64];        // 16KB Kh stage
  const int tid  = threadIdx.x;
  const int lane = tid & 63, wave = tid >> 6;
  const int c = lane & 15, quad = lane >> 4;
  const int bh = blockIdx.x;
  const int qg = blockIdx.y;
  const int kz = blockIdx.z * 1024;                   // key-half base
  const int q0 = qg * 64 + wave * 16;
  const size_t hoff = (size_t)bh * SEQ * HD;
  const bf16* qh_p = Qh + hoff;
  const bf16* kh_p = Kh + hoff + (size_t)kz * HD;
  const f32x4 zero = {0.f, 0.f, 0.f, 0.f};

  const int sr   = tid >> 3;                          // 0..31 staging row
  const int scol = (tid & 7) * 8;
  const int sphy = ((tid & 7) ^ (sr & 7)) * 8;
  const int pc0  = ((0 + quad) ^ (c & 7)) * 8;
  const int pc1  = ((4 + quad) ^ (c & 7)) * 8;
  const int gq   = (bh * 32 + qg) * 64 + wave * 16 + c;   // global query id

  bf16x8 qf[2];
#pragma unroll
  for (int t = 0; t < 2; ++t)
    qf[t] = *(const bf16x8*)&qh_p[(size_t)(q0 + c) * HD + t * 32 + quad * 8];

  bf16x8 pA = *(const bf16x8*)&kh_p[(size_t)(sr     ) * HD + scol];
  bf16x8 pB = *(const bf16x8*)&kh_p[(size_t)(sr + 32) * HD + scol];
  *(bf16x8*)&SK[0][sr     ][sphy] = pA;
  *(bf16x8*)&SK[0][sr + 32][sphy] = pB;
  __syncthreads();

  float mr = NEG_SEED;
  int buf = 0;
  for (int cs = 0; cs < 16; ++cs) {
    if (cs < 15) {
      const size_t k0 = (size_t)(cs + 1) * 64;
      pA = *(const bf16x8*)&kh_p[(k0 + sr     ) * HD + scol];
      pB = *(const bf16x8*)&kh_p[(k0 + sr + 32) * HD + scol];
    }
#pragma unroll
    for (int t = 0; t < 4; ++t) {
      const int g = cs * 4 + t;
      bf16x8 kh0 = *(bf16x8*)&SK[buf][t * 16 + c][pc0];
      bf16x8 kh1 = *(bf16x8*)&SK[buf][t * 16 + c][pc1];
      f32x4 sc = MFMA(kh0, qf[0], zero);
      sc = MFMA(kh1, qf[1], sc);
      const float tm = fmaxf(fmaxf(sc[0], sc[1]), fmaxf(sc[2], sc[3]));
      mr = fmaxf(mr, tm);
      if (t & 1) {   // quad-share the running max every 2 tiles
        mr = fmaxf(mr, __shfl_xor(mr, 16, 64));
        mr = fmaxf(mr, __shfl_xor(mr, 32, 64));
      }
      if (tm > mr - 12.f) {
#pragma unroll
        for (int r = 0; r < 4; ++r) {
          if (sc[r] > mr - 12.f) {
            const int slot = atomicAdd(&PcntG[gq], 1) & (LCAP - 1);  // ring
            CandG[(size_t)gq * LCAP + slot] =
                (unsigned short)(kz + g * 16 + quad * 4 + r);
          }
        }
      }
    }
    if (cs < 15) {
      const int nb = buf ^ 1;
      *(bf16x8*)&SK[nb][sr     ][sphy] = pA;
      *(bf16x8*)&SK[nb][sr + 32][sphy] = pB;
      __syncthreads();
      buf = nb;
    }
  }
}

// ---------------------------------------------------------------------------
// Attention FINISH (tiny): exact fp32 VALU dot for the ~12 listed candidates
// per query (union of both halves), exact max, l1 = sum exp (shift-invariant;
// non-candidate tail < 3e-4 rel), t-1 = exp(p/l1)-1, V-row gather, + Vtot.
// ---------------------------------------------------------------------------
__global__ __launch_bounds__(256)
void attn_finish(const bf16* __restrict__ Qh, const bf16* __restrict__ Ql,
                 const bf16* __restrict__ Kh, const bf16* __restrict__ Kl,
                 const bf16* __restrict__ Vrm, const float* __restrict__ Vs,
                 const unsigned short* __restrict__ CandG,
                 const int* __restrict__ PcntG, bf16* __restrict__ O) {
  __shared__ float sS[4][16][LCAP];
  const int tid  = threadIdx.x;
  const int lane = tid & 63, wave = tid >> 6;
  const int c = lane & 15, quad = lane >> 4;
  const int bh = blockIdx.x;
  const int qg = blockIdx.y;
  const int q0 = qg * 64 + wave * 16;
  const size_t hoff = (size_t)bh * SEQ * HD;
  const bf16* kh_p = Kh + hoff;
  const bf16* kl_p = Kl + hoff;
  const bf16* v_p  = Vrm + hoff;
  const int gq = (bh * 32 + qg) * 64 + wave * 16 + c;

  bf16x8 qf[2], qlf[2];
#pragma unroll
  for (int t = 0; t < 2; ++t) {
    size_t off = (size_t)(q0 + c) * HD + t * 32 + quad * 8;
    qf[t]  = *(const bf16x8*)&Qh[hoff + off];
    qlf[t] = *(const bf16x8*)&Ql[hoff + off];
  }
  float qv[16];
#pragma unroll
  for (int j = 0; j < 8; ++j) {
    qv[j]     = (float)qf[0][j] + (float)qlf[0][j];
    qv[8 + j] = (float)qf[1][j] + (float)qlf[1][j];
  }

  const int n = min(PcntG[gq], LCAP);
  float mqC = NEG_SEED;
  for (int j = 0; j < n; ++j) {
    const int idx = CandG[(size_t)gq * LCAP + j];
    const size_t kr = (size_t)idx * HD + quad * 8;
    bf16x8 kh0 = *(const bf16x8*)&kh_p[kr];
    bf16x8 kh1 = *(const bf16x8*)&kh_p[kr + 32];
    bf16x8 kl0 = *(const bf16x8*)&kl_p[kr];
    bf16x8 kl1 = *(const bf16x8*)&kl_p[kr + 32];
    float s = 0.f;
#pragma unroll
    for (int jj = 0; jj < 8; ++jj) {
      s = fmaf(qv[jj],     (float)kh0[jj] + (float)kl0[jj], s);
      s = fmaf(qv[8 + jj], (float)kh1[jj] + (float)kl1[jj], s);
    }
    s += __shfl_xor(s, 16, 64);
    s += __shfl_xor(s, 32, 64);
    if (quad == 0) sS[wave][c][j] = s;
    mqC = fmaxf(mqC, s);
  }
  float l1 = 0.f;
  for (int j = 0; j < n; ++j) l1 += __expf(sS[wave][c][j] - mqC);
  const float inv1 = 1.f / l1;

  float oc[16];
#pragma unroll
  for (int i = 0; i < 16; ++i) oc[i] = 0.f;
  float l2 = 0.f;
  for (int j = 0; j < n; ++j) {
    const float a1 = __expf(sS[wave][c][j] - mqC) * inv1;  // attn1 in [0,1]
    const float t1 = __expf(a1) - 1.0f;                    // t-1
    l2 += t1;
    const int idx = CandG[(size_t)gq * LCAP + j];
    bf16x8 v0 = *(const bf16x8*)&v_p[(size_t)idx * HD + quad * 8];
    bf16x8 v1 = *(const bf16x8*)&v_p[(size_t)idx * HD + 32 + quad * 8];
#pragma unroll
    for (int jj = 0; jj < 8; ++jj) {
      oc[jj]     += t1 * (float)v0[jj];
      oc[8 + jj] += t1 * (float)v1[jj];
    }
  }

  const int b = bh >> 3, h = bh & 7;
  const float rcp = 1.f / (2048.f + l2);
  const float* vsp = Vs + bh * HD;
  bf16* orow = &O[((size_t)b * SEQ + q0 + c) * EMB + h * HD];
  bf16x8 o0, o1;
#pragma unroll
  for (int jj = 0; jj < 8; ++jj) {
    o0[jj] = (bf16)((oc[jj]     + vsp[quad * 8 + jj])      * rcp);
    o1[jj] = (bf16)((oc[8 + jj] + vsp[32 + quad * 8 + jj]) * rcp);
  }
  *(bf16x8*)&orow[quad * 8]      = o0;
  *(bf16x8*)&orow[32 + quad * 8] = o1;
}

// ---------------------------------------------------------------------------
extern "C" void kernel_launch(void* const* d_in, const int* in_sizes, int n_in,
                              void* d_out, int out_size, void* d_ws, size_t ws_size,
                              hipStream_t stream) {
  const float* x    = (const float*)d_in[0];
  const float* Wqkv = (const float*)d_in[1];
  const float* bqkv = (const float*)d_in[2];
  const float* Wout = (const float*)d_in[3];
  const float* bout = (const float*)d_in[4];
  float* out = (float*)d_out;

  char* ws = (char*)d_ws;
  const size_t SZ = (size_t)32 * SEQ * HD * 2;  // 8 MiB per array
  bf16* Qh  = (bf16*)(ws + 0 * SZ);
  bf16* Ql  = (bf16*)(ws + 1 * SZ);
  bf16* Kh  = (bf16*)(ws + 2 * SZ);
  bf16* Kl  = (bf16*)(ws + 3 * SZ);
  bf16* Vrm = (bf16*)(ws + 4 * SZ);
  bf16* XhO = (bf16*)(ws + 5 * SZ);  // Xh during proj; overwritten by O
  bf16* Xl  = (bf16*)(ws + 6 * SZ);  // dead after gemm_qkv -> CandG reuses it
  bf16* Wqh = (bf16*)(ws + 7 * SZ);
  bf16* Wql = (bf16*)(ws + 7 * SZ + 0x180000);
  bf16* Wo  = (bf16*)(ws + 7 * SZ + 0x300000);
  float* Vs = (float*)(ws + 7 * SZ + 0x380000);        // 32x64 f32 (8KB)
  int* PcntG = (int*)(ws + 7 * SZ + 0x382000);         // 65536 ints (256KB)
  unsigned short* CandG = (unsigned short*)(ws + 6 * SZ);  // 4MB in Xl region

  convert_kernel<<<dim3(2048), 256, 0, stream>>>(x, Wqkv, Wout, XhO, Xl, Wqh, Wql, Wo, Vs, PcntG);
  gemm_qkv<<<dim3(128, 24), 256, 0, stream>>>(XhO, Xl, Wqh, Wql, bqkv, Qh, Ql, Kh, Kl, Vrm, Vs);
  attn_scan<<<dim3(32, 32, 2), 256, 0, stream>>>(Qh, Kh, CandG, PcntG);
  attn_finish<<<dim3(32, 32), 256, 0, stream>>>(Qh, Ql, Kh, Kl, Vrm, Vs, CandG, PcntG, XhO);
  gemm_out<<<dim3(128, 8), 256, 0, stream>>>(XhO, Wo, bout, out);
}